// Round 18
// baseline (121.774 us; speedup 1.0000x reference)
//
#include <hip/hip_runtime.h>
#include <math.h>

typedef unsigned int  u32;
typedef unsigned short u16;
typedef unsigned long long u64;

// Problem constants (B=4, S=2048, D=1024, R=128, N=64, K=8)
#define T_TOK 8192
#define DDIM  1024
#define RDIM  128
#define NEXP  64
#define TOPK  8
#define NENT  (T_TOK * TOPK)   // 65536
#define NCHUNK 256             // chunks of 256 entries

// d_out layout (floats), reference return order: output, weights, topk_idx, scores
#define OUT_O_OFF 0
#define OUT_W_OFF (T_TOK * RDIM)                 // 1048576
#define OUT_I_OFF (OUT_W_OFF + T_TOK * TOPK)     // 1114112
#define OUT_S_OFF (OUT_I_OFF + T_TOK * TOPK)     // 1179648

// ws layout (bytes)
//   0        counts    int[64]
//   256      offsets   int[64]
//   1024     list_tk   int[65536]
//   263168   idx_int   int[65536]
//   525312   histT     int[64*256]   [525312, 590848)
//   590848   chunk_off int[64*256]   [590848, 656384)
//   656384   x_bf      u16[8192*1024]      (16 MB)
//   +16M     cn_bt     u16[64*128*1024]    (16 MB, [n][r][d])
//   +32M     proj_bf   u16[65536*128]      (16 MB)
//   +48M     partials  double[nslice][8192][64] (32 MB @ nslice=8)

typedef __attribute__((ext_vector_type(8))) short bf16x8;
typedef __attribute__((ext_vector_type(4))) float f32x4;

__device__ __forceinline__ u16 f2bf(float f) {
  union { float f; u32 u; } v; v.f = f;
  u32 r = v.u + 0x7fffu + ((v.u >> 16) & 1u);   // RNE
  return (u16)(r >> 16);
}
__device__ __forceinline__ float bf2f(u16 h) {
  union { u32 u; float f; } v; v.u = ((u32)h) << 16;
  return v.f;
}

// async global->LDS, 16B per lane; LDS dest = wave-uniform base + lane*16
#define GL_LDS(gp, lp) __builtin_amdgcn_global_load_lds( \
    (const __attribute__((address_space(1))) void*)(gp), \
    (__attribute__((address_space(3))) void*)(lp), 16, 0, 0)

// ---------------------------------------------------------------------------
// convert x fp32 -> bf16 (fallback path only; sliced router writes xbf itself)
// ---------------------------------------------------------------------------
__global__ __launch_bounds__(256) void convert_x_kernel(
    const float* __restrict__ x, u16* __restrict__ xbf)
{
  const int i = blockIdx.x * 256 + threadIdx.x;   // 0 .. 1048575
  const float4 a = reinterpret_cast<const float4*>(x)[i * 2];
  const float4 b = reinterpret_cast<const float4*>(x)[i * 2 + 1];
  uint4 o;
  o.x = (u32)f2bf(a.x) | ((u32)f2bf(a.y) << 16);
  o.y = (u32)f2bf(a.z) | ((u32)f2bf(a.w) << 16);
  o.z = (u32)f2bf(b.x) | ((u32)f2bf(b.y) << 16);
  o.w = (u32)f2bf(b.z) | ((u32)f2bf(b.w) << 16);
  reinterpret_cast<uint4*>(xbf)[i] = o;
}

// ---------------------------------------------------------------------------
// transpose+convert cn [n][d][r] fp32 -> cn_bt [n][r][d] bf16, 32x32 tiles
// ---------------------------------------------------------------------------
__global__ __launch_bounds__(256) void convert_cn_kernel(
    const float* __restrict__ cn, u16* __restrict__ cnbt)
{
  const int n  = blockIdx.x;
  const int d0 = blockIdx.y * 32;
  const int r0 = blockIdx.z * 32;
  __shared__ float ts[32][33];
  const int t = threadIdx.x;
  {
    const int dr = t >> 3, rq = t & 7;
    float4 v = *reinterpret_cast<const float4*>(
        cn + ((size_t)n * DDIM + d0 + dr) * RDIM + r0 + rq * 4);
    ts[dr][rq * 4 + 0] = v.x; ts[dr][rq * 4 + 1] = v.y;
    ts[dr][rq * 4 + 2] = v.z; ts[dr][rq * 4 + 3] = v.w;
  }
  __syncthreads();
  {
    const int rr = t >> 3, dq = t & 7;
    ushort4 o;
    o.x = f2bf(ts[dq * 4 + 0][rr]);
    o.y = f2bf(ts[dq * 4 + 1][rr]);
    o.z = f2bf(ts[dq * 4 + 2][rr]);
    o.w = f2bf(ts[dq * 4 + 3][rr]);
    *reinterpret_cast<ushort4*>(
        cnbt + ((size_t)n * RDIM + r0 + rr) * DDIM + d0 + dq * 4) = o;
  }
}

// ---------------------------------------------------------------------------
// Router v6: LDS-READ-THROUGHPUT fix.  The 41-us plateau = 2.1M ds_read_b128
// x 12cyc / 256 CU (model matches measurement exactly; VALUBusy 34% = 13.7us
// fp64 floor / 41us LDS wall).  Cut reads/MAC: 8 tok x 4 exp per thread
// (block tile 128 tok x 64 exp) -> 12 b128 reads per 64 MACs (was 8 per 32).
// LDS 57 KB (xs[128][38] + wsd[64][38]); stride 38 keeps 2-way banks (free).
// Same ascending-d order per acc; topk folds slices ascending ->
// bit-identical scores.  Fused bf16 x side-write.
// ---------------------------------------------------------------------------
__global__ __launch_bounds__(256) void router_part_kernel(
    const float* __restrict__ x, const float* __restrict__ rw,
    double* __restrict__ partials, u16* __restrict__ xbf, int dlen)
{
  __shared__ double xs[128][38];
  __shared__ double wsd[64][38];

  const int tok0  = blockIdx.x * 128;
  const int slice = blockIdx.y;
  const int d0    = slice * dlen;
  const int t     = threadIdx.x;
  const int ti    = t & 15;
  const int ei    = t >> 4;

  // staging: x: 2 threads/row (row t>>1), 4 float4 each at (t&1)*16 + i*4
  //          w: 4 threads/row (row t>>2), 2 float4 each at (t&3)*8 + i*4
  const int xrow = t >> 1;
  const int xq   = (t & 1) * 16;
  const int wrow = t >> 2;
  const int wq   = (t & 3) * 8;

  double acc[8][4];
#pragma unroll
  for (int a = 0; a < 8; ++a)
#pragma unroll
    for (int b = 0; b < 4; ++b) acc[a][b] = 0.0;

  for (int dc = d0; dc < d0 + dlen; dc += 32) {
    // stage x (128 rows x 32 d) + bf16 side-write; convert once to fp64
#pragma unroll
    for (int i = 0; i < 4; ++i) {
      const int dd = xq + i * 4;
      float4 v = *reinterpret_cast<const float4*>(
          x + (size_t)(tok0 + xrow) * DDIM + dc + dd);
      double2 p0; p0.x = (double)v.x; p0.y = (double)v.y;
      double2 p1; p1.x = (double)v.z; p1.y = (double)v.w;
      *reinterpret_cast<double2*>(&xs[xrow][dd])     = p0;
      *reinterpret_cast<double2*>(&xs[xrow][dd + 2]) = p1;
      ushort4 o;
      o.x = f2bf(v.x); o.y = f2bf(v.y); o.z = f2bf(v.z); o.w = f2bf(v.w);
      *reinterpret_cast<ushort4*>(
          xbf + (size_t)(tok0 + xrow) * DDIM + dc + dd) = o;
    }
    // stage rw (64 rows x 32 d)
#pragma unroll
    for (int i = 0; i < 2; ++i) {
      const int dd = wq + i * 4;
      float4 wv = *reinterpret_cast<const float4*>(
          rw + (size_t)wrow * DDIM + dc + dd);
      double2 q0; q0.x = (double)wv.x; q0.y = (double)wv.y;
      double2 q1; q1.x = (double)wv.z; q1.y = (double)wv.w;
      *reinterpret_cast<double2*>(&wsd[wrow][dd])     = q0;
      *reinterpret_cast<double2*>(&wsd[wrow][dd + 2]) = q1;
    }
    __syncthreads();

#pragma unroll 2
    for (int d2 = 0; d2 < 32; d2 += 2) {
      double2 wv0 = *reinterpret_cast<const double2*>(&wsd[ei +  0][d2]);
      double2 wv1 = *reinterpret_cast<const double2*>(&wsd[ei + 16][d2]);
      double2 wv2 = *reinterpret_cast<const double2*>(&wsd[ei + 32][d2]);
      double2 wv3 = *reinterpret_cast<const double2*>(&wsd[ei + 48][d2]);
#pragma unroll
      for (int j = 0; j < 8; ++j) {
        double2 xv = *reinterpret_cast<const double2*>(&xs[ti + 16 * j][d2]);
        acc[j][0] += xv.x * wv0.x; acc[j][0] += xv.y * wv0.y;
        acc[j][1] += xv.x * wv1.x; acc[j][1] += xv.y * wv1.y;
        acc[j][2] += xv.x * wv2.x; acc[j][2] += xv.y * wv2.y;
        acc[j][3] += xv.x * wv3.x; acc[j][3] += xv.y * wv3.y;
      }
    }
    __syncthreads();
  }

#pragma unroll
  for (int jt = 0; jt < 8; ++jt)
#pragma unroll
    for (int je = 0; je < 4; ++je)
      partials[((size_t)slice * T_TOK + tok0 + ti + 16 * jt) * NEXP
               + ei + 16 * je] = acc[jt][je];
}

// ---------------------------------------------------------------------------
// Fallback single-pass router (round-5/6 proven): fp32 LDS, fp64 acc.
// ---------------------------------------------------------------------------
__global__ __launch_bounds__(256) void router_gemm_kernel(
    const float* __restrict__ x, const float* __restrict__ rw,
    float* __restrict__ out)
{
  __shared__ float xs[32][68];
  __shared__ float wsm[64][68];
  const int tok0 = blockIdx.x * 32;
  const int t  = threadIdx.x;
  const int ti2 = (t & 15) * 2;
  const int e4  = (t >> 4) * 4;

  double acc[2][4];
#pragma unroll
  for (int a = 0; a < 2; ++a)
#pragma unroll
    for (int b = 0; b < 4; ++b) acc[a][b] = 0.0;

  for (int dc = 0; dc < DDIM; dc += 64) {
#pragma unroll
    for (int p = 0; p < 2; ++p) {
      const int idx = t + p * 256;
      const int row = idx >> 4, q = idx & 15;
      float4 v = *reinterpret_cast<const float4*>(
          x + (size_t)(tok0 + row) * DDIM + dc + q * 4);
      *reinterpret_cast<float4*>(&xs[row][q * 4]) = v;
    }
#pragma unroll
    for (int p = 0; p < 4; ++p) {
      const int idx = t + p * 256;
      const int row = idx >> 4, q = idx & 15;
      float4 v = *reinterpret_cast<const float4*>(
          rw + (size_t)row * DDIM + dc + q * 4);
      *reinterpret_cast<float4*>(&wsm[row][q * 4]) = v;
    }
    __syncthreads();

#pragma unroll 2
    for (int d4 = 0; d4 < 64; d4 += 4) {
      float4 xv0 = *reinterpret_cast<const float4*>(&xs[ti2][d4]);
      float4 xv1 = *reinterpret_cast<const float4*>(&xs[ti2 + 1][d4]);
      float4 wv0 = *reinterpret_cast<const float4*>(&wsm[e4 + 0][d4]);
      float4 wv1 = *reinterpret_cast<const float4*>(&wsm[e4 + 1][d4]);
      float4 wv2 = *reinterpret_cast<const float4*>(&wsm[e4 + 2][d4]);
      float4 wv3 = *reinterpret_cast<const float4*>(&wsm[e4 + 3][d4]);
      acc[0][0] += (double)xv0.x * (double)wv0.x; acc[0][0] += (double)xv0.y * (double)wv0.y;
      acc[0][0] += (double)xv0.z * (double)wv0.z; acc[0][0] += (double)xv0.w * (double)wv0.w;
      acc[0][1] += (double)xv0.x * (double)wv1.x; acc[0][1] += (double)xv0.y * (double)wv1.y;
      acc[0][1] += (double)xv0.z * (double)wv1.z; acc[0][1] += (double)xv0.w * (double)wv1.w;
      acc[0][2] += (double)xv0.x * (double)wv2.x; acc[0][2] += (double)xv0.y * (double)wv2.y;
      acc[0][2] += (double)xv0.z * (double)wv2.z; acc[0][2] += (double)xv0.w * (double)wv2.w;
      acc[0][3] += (double)xv0.x * (double)wv3.x; acc[0][3] += (double)xv0.y * (double)wv3.y;
      acc[0][3] += (double)xv0.z * (double)wv3.z; acc[0][3] += (double)xv0.w * (double)wv3.w;
      acc[1][0] += (double)xv1.x * (double)wv0.x; acc[1][0] += (double)xv1.y * (double)wv0.y;
      acc[1][0] += (double)xv1.z * (double)wv0.z; acc[1][0] += (double)xv1.w * (double)wv0.w;
      acc[1][1] += (double)xv1.x * (double)wv1.x; acc[1][1] += (double)xv1.y * (double)wv1.y;
      acc[1][1] += (double)xv1.z * (double)wv1.z; acc[1][1] += (double)xv1.w * (double)wv1.w;
      acc[1][2] += (double)xv1.x * (double)wv2.x; acc[1][2] += (double)xv1.y * (double)wv2.y;
      acc[1][2] += (double)xv1.z * (double)wv2.z; acc[1][2] += (double)xv1.w * (double)wv2.w;
      acc[1][3] += (double)xv1.x * (double)wv3.x; acc[1][3] += (double)xv1.y * (double)wv3.y;
      acc[1][3] += (double)xv1.z * (double)wv3.z; acc[1][3] += (double)xv1.w * (double)wv3.w;
    }
    __syncthreads();
  }

#pragma unroll
  for (int a = 0; a < 2; ++a) {
    float4 o;
    o.x = (float)acc[a][0]; o.y = (float)acc[a][1];
    o.z = (float)acc[a][2]; o.w = (float)acc[a][3];
    *reinterpret_cast<float4*>(
        out + OUT_S_OFF + (size_t)(tok0 + ti2 + a) * NEXP + e4) = o;
  }
}

// ---------------------------------------------------------------------------
// Top-8 + softmax. 4 tokens per 256-thread block (one wave each). No atomics.
// ---------------------------------------------------------------------------
__global__ __launch_bounds__(256) void topk_kernel(
    const double* __restrict__ partials,
    float* __restrict__ out, int* __restrict__ idx_int, int nslice)
{
  const int token = blockIdx.x * 4 + (threadIdx.x >> 6);
  const int lane  = threadIdx.x & 63;

  float v;
  if (nslice > 0) {
    double s = 0.0;
    for (int sl = 0; sl < nslice; ++sl)
      s += partials[((size_t)sl * T_TOK + token) * NEXP + lane];
    v = (float)s;
    out[OUT_S_OFF + (size_t)token * NEXP + lane] = v;
  } else {
    v = out[OUT_S_OFF + (size_t)token * NEXP + lane];
  }

  float cur = v;
  float topv[TOPK];
  int   topi[TOPK];
  for (int k = 0; k < TOPK; ++k) {
    float bv = cur;
    int   bi = lane;
#pragma unroll
    for (int off = 32; off >= 1; off >>= 1) {
      float ov = __shfl_xor(bv, off);
      int   oi = __shfl_xor(bi, off);
      if (ov > bv || (ov == bv && oi < bi)) { bv = ov; bi = oi; }
    }
    topv[k] = bv;
    topi[k] = bi;
    if (lane == bi) cur = -INFINITY;
  }
  const float m = topv[0];
  float wk[TOPK];
  float s = 0.f;
#pragma unroll
  for (int k = 0; k < TOPK; ++k) { wk[k] = expf(topv[k] - m); s += wk[k]; }
  const float inv = 1.f / s;

  if (lane < TOPK) {
    out[OUT_W_OFF + (size_t)token * TOPK + lane] = wk[lane] * inv;
    out[OUT_I_OFF + (size_t)token * TOPK + lane] = (float)topi[lane];
    idx_int[(size_t)token * TOPK + lane] = topi[lane];
  }
}

// ---------------------------------------------------------------------------
// Compaction phase A: per-chunk expert histogram (ballot, no atomics).
// ---------------------------------------------------------------------------
__global__ __launch_bounds__(256) void hist_kernel(
    const int* __restrict__ idx_int, int* __restrict__ histT)
{
  const int chunk = blockIdx.x;
  const int t = threadIdx.x;
  const int w = t >> 6, l = t & 63;
  const int v = idx_int[chunk * 256 + t];

  __shared__ int wh[4][64];
  int cnt = 0;
#pragma unroll 8
  for (int s = 0; s < NEXP; ++s) {
    const u64 b = __ballot(v == s);
    if (l == s) cnt = (int)__popcll(b);
  }
  wh[w][l] = cnt;
  __syncthreads();
  if (t < NEXP)
    histT[t * NCHUNK + chunk] = wh[0][t] + wh[1][t] + wh[2][t] + wh[3][t];
}

// ---------------------------------------------------------------------------
// Compaction phase B, PARALLEL: 64 blocks (one per expert).
// ---------------------------------------------------------------------------
__global__ __launch_bounds__(256) void offsets_kernel(
    const int* __restrict__ histT, int* __restrict__ chunk_off,
    int* __restrict__ counts, int* __restrict__ offsets)
{
  const int n = blockIdx.x;
  const int t = threadIdx.x;
  const int w = t >> 6, l = t & 63;
  __shared__ int bsum[4];
  __shared__ int wsum[4];

  int part = 0;
  for (int i = t; i < n * NCHUNK; i += 256) part += histT[i];
#pragma unroll
  for (int off = 32; off >= 1; off >>= 1) part += __shfl_xor(part, off);
  if (l == 0) bsum[w] = part;
  __syncthreads();
  const int base = bsum[0] + bsum[1] + bsum[2] + bsum[3];

  const int h = histT[n * NCHUNK + t];
  int s = h;
#pragma unroll
  for (int off = 1; off < 64; off <<= 1) {
    const int o = __shfl_up(s, off);
    if (l >= off) s += o;
  }
  if (l == 63) wsum[w] = s;
  __syncthreads();
  int wpre = 0;
#pragma unroll
  for (int w2 = 0; w2 < 4; ++w2) if (w2 < w) wpre += wsum[w2];
  const int incl = s + wpre;

  chunk_off[n * NCHUNK + t] = base + incl - h;
  if (t == 255) counts[n] = incl;
  if (t == 0)   offsets[n] = base;
}

// ---------------------------------------------------------------------------
// Compaction phase C: stable scatter via ballot rank + per-wave hist prefix.
// ---------------------------------------------------------------------------
__global__ __launch_bounds__(256) void scatter_kernel(
    const int* __restrict__ idx_int, const int* __restrict__ chunk_off,
    int* __restrict__ list_tk)
{
  const int chunk = blockIdx.x;
  const int t = threadIdx.x;
  const int w = t >> 6, l = t & 63;
  const int e = chunk * 256 + t;
  const int v = idx_int[e];

  __shared__ int wh[4][64];
  int myrank = 0, cnt = 0;
#pragma unroll 8
  for (int s = 0; s < NEXP; ++s) {
    const u64 b = __ballot(v == s);
    if (v == s) myrank = (int)__popcll(b & ((1ull << l) - 1ull));
    if (l == s) cnt = (int)__popcll(b);
  }
  wh[w][l] = cnt;
  __syncthreads();
  int pre = 0;
#pragma unroll
  for (int w2 = 0; w2 < 4; ++w2) if (w2 < w) pre += wh[w2][v];
  list_tk[chunk_off[v * NCHUNK + chunk] + pre + myrank] = e;
}

// ---------------------------------------------------------------------------
// MFMA expert GEMM v4 (round-14/15 proven) + T5 setprio around MFMA cluster.
// 64-token tile, 48 KB dbuf LDS, pre-swizzled GL_LDS, counted-vmcnt pipeline.
// ---------------------------------------------------------------------------
template<int MODE>
__global__ __launch_bounds__(256) void mfma_gemm_kernel(
    const u16* __restrict__ xbf, const u16* __restrict__ cnbt,
    const int* __restrict__ counts, const int* __restrict__ offsets,
    const int* __restrict__ list_tk,
    float* __restrict__ out, u16* __restrict__ projbf)
{
  const int n = blockIdx.x;
  const int cnt = counts[n];
  const int start = blockIdx.y * 64;
  if (start >= cnt) return;
  const int nrows = min(64, cnt - start);
  const int base = offsets[n] + start;

  __shared__ __align__(16) u16 smem[2 * 12288];   // 48 KB

  const int t  = threadIdx.x;
  const int l  = t & 63;
  const int w  = t >> 6;
  const int cl = l & 15;
  const int kq = l >> 4;

  const int rsub = l >> 3;                 // 0..7
  const int p8   = ((l & 7) ^ rsub) * 8;   // swizzled u16 offset in row

  int toki[2];
#pragma unroll
  for (int i = 0; i < 2; ++i) {
    const int r = w * 16 + i * 8 + rsub;
    toki[i] = list_tk[base + min(r, nrows - 1)] >> 3;
  }
  const u16* cnb = cnbt + (size_t)n * RDIM * DDIM;

  f32x4 acc[8];
#pragma unroll
  for (int f = 0; f < 8; ++f) acc[f] = (f32x4){0.f, 0.f, 0.f, 0.f};

  // prologue: stage chunk 0 into buffer 0 (6 GL_LDS per thread)
#pragma unroll
  for (int i = 0; i < 2; ++i) {
    const int rs = w * 16 + i * 8;
    GL_LDS(xbf + (size_t)toki[i] * DDIM + p8, smem + rs * 64);
  }
#pragma unroll
  for (int i = 0; i < 4; ++i) {
    const int rs = w * 32 + i * 8;
    GL_LDS(cnb + (size_t)(rs + rsub) * DDIM + p8, smem + 4096 + rs * 64);
  }

  int cur = 0;
  for (int c = 0; c < 16; ++c) {
    if (c < 15) {
      const int dc = (c + 1) * 64;
      const int po = (cur ^ 1) * 12288;
#pragma unroll
      for (int i = 0; i < 2; ++i) {
        const int rs = w * 16 + i * 8;
        GL_LDS(xbf + (size_t)toki[i] * DDIM + dc + p8, smem + po + rs * 64);
      }
#pragma unroll
      for (int i = 0; i < 4; ++i) {
        const int rs = w * 32 + i * 8;
        GL_LDS(cnb + (size_t)(rs + rsub) * DDIM + dc + p8,
               smem + po + 4096 + rs * 64);
      }
      asm volatile("s_waitcnt vmcnt(6)" ::: "memory");
    } else {
      asm volatile("s_waitcnt vmcnt(0)" ::: "memory");
    }
    __builtin_amdgcn_s_barrier();          // all waves' chunk-c data in LDS
    __builtin_amdgcn_sched_barrier(0);     // pin: no ds_read hoists above

    const u16* A = smem + cur * 12288;
    const u16* B = A + 4096;
    __builtin_amdgcn_s_setprio(1);
#pragma unroll
    for (int ks = 0; ks < 2; ++ks) {
      const int piece = ks * 4 + kq;
      const int ar = w * 16 + cl;
      bf16x8 a = *reinterpret_cast<const bf16x8*>(
          &A[ar * 64 + ((piece ^ (ar & 7)) * 8)]);
#pragma unroll
      for (int f = 0; f < 8; ++f) {
        const int br = f * 16 + cl;
        bf16x8 b = *reinterpret_cast<const bf16x8*>(
            &B[br * 64 + ((piece ^ (br & 7)) * 8)]);
        acc[f] = __builtin_amdgcn_mfma_f32_16x16x32_bf16(a, b, acc[f], 0, 0, 0);
      }
    }
    __builtin_amdgcn_s_setprio(0);
    asm volatile("s_waitcnt lgkmcnt(0)" ::: "memory");  // reads of cur done
    __builtin_amdgcn_s_barrier();          // before next iter overwrites cur
    cur ^= 1;
  }

  // epilogue: C/D layout row=(l>>4)*4+reg, col = f*16 + (l&15)
#pragma unroll
  for (int j = 0; j < 4; ++j) {
    const int row = w * 16 + kq * 4 + j;
    if (row < nrows) {
      const int tk = list_tk[base + row];
      if (MODE == 0) {
        u16* prow = projbf + (size_t)tk * RDIM + cl;
#pragma unroll
        for (int f = 0; f < 8; ++f) prow[f * 16] = f2bf(acc[f][j]);
      } else {
        const float wg = out[OUT_W_OFF + tk];
        float* orow = out + OUT_O_OFF + (size_t)(tk >> 3) * RDIM + cl;
#pragma unroll
        for (int f = 0; f < 8; ++f) unsafeAtomicAdd(&orow[f * 16], wg * acc[f][j]);
      }
    }
  }
}

// ---------------------------------------------------------------------------
// Combine: out[tok][r] = sum_k w[tok][k] * proj[tok*8+k][r].  Wave per token.
// ---------------------------------------------------------------------------
__global__ __launch_bounds__(256) void combine_kernel(
    const u16* __restrict__ projbf, float* __restrict__ out)
{
  const int token = blockIdx.x * 4 + (threadIdx.x >> 6);
  const int l = threadIdx.x & 63;
  float wts[TOPK];
#pragma unroll
  for (int k = 0; k < TOPK; ++k) wts[k] = out[OUT_W_OFF + (size_t)token * TOPK + k];
  float s0 = 0.f, s1 = 0.f;
#pragma unroll
  for (int k = 0; k < TOPK; ++k) {
    const u32 u = *reinterpret_cast<const u32*>(
        projbf + ((size_t)token * TOPK + k) * RDIM + l * 2);
    s0 += wts[k] * bf2f((u16)(u & 0xffff));
    s1 += wts[k] * bf2f((u16)(u >> 16));
  }
  float2 o; o.x = s0; o.y = s1;
  *reinterpret_cast<float2*>(out + OUT_O_OFF + (size_t)token * RDIM + l * 2) = o;
}

// ---------------------------------------------------------------------------
// Tier-2 fallback: fp32 gemm, weight read via tk (64-row tile, grid y=128).
// ---------------------------------------------------------------------------
__global__ __launch_bounds__(256) void gemm_f32_kernel(
    const float* __restrict__ x, const float* __restrict__ cn,
    const int* __restrict__ counts, const int* __restrict__ offsets,
    const int* __restrict__ list_tk, float* __restrict__ out)
{
  const int n = blockIdx.x;
  const int cnt = counts[n];
  const int start = blockIdx.y * 64;
  if (start >= cnt) return;
  const int nrows = min(64, cnt - start);
  const int base = offsets[n] + start;

  __shared__ float xs[64][33];
  __shared__ float cs[32][RDIM];

  const int t  = threadIdx.x;
  const int tg = t & 31;
  const int rc = t >> 5;
  const int row0 = tg * 2, row1 = tg * 2 + 1;
  const int rA = t >> 3, rB = rA + 32, jA = t & 7;
  const int tokA = (rA < nrows) ? (list_tk[base + rA] >> 3) : -1;
  const int tokB = (rB < nrows) ? (list_tk[base + rB] >> 3) : -1;

  float acc0[16], acc1[16];
#pragma unroll
  for (int j = 0; j < 16; ++j) { acc0[j] = 0.f; acc1[j] = 0.f; }
  const float* cbase = cn + (size_t)n * DDIM * RDIM;

  for (int dc = 0; dc < DDIM; dc += 32) {
    {
      float4 v = make_float4(0.f, 0.f, 0.f, 0.f);
      if (tokA >= 0) v = *reinterpret_cast<const float4*>(x + (size_t)tokA * DDIM + dc + jA * 4);
      xs[rA][jA * 4 + 0] = v.x; xs[rA][jA * 4 + 1] = v.y;
      xs[rA][jA * 4 + 2] = v.z; xs[rA][jA * 4 + 3] = v.w;
      float4 u = make_float4(0.f, 0.f, 0.f, 0.f);
      if (tokB >= 0) u = *reinterpret_cast<const float4*>(x + (size_t)tokB * DDIM + dc + jA * 4);
      xs[rB][jA * 4 + 0] = u.x; xs[rB][jA * 4 + 1] = u.y;
      xs[rB][jA * 4 + 2] = u.z; xs[rB][jA * 4 + 3] = u.w;
    }
#pragma unroll
    for (int p = 0; p < 4; ++p) {
      const int f = t + p * 256;
      const int dr = f >> 5, c4 = f & 31;
      float4 v = *reinterpret_cast<const float4*>(cbase + (size_t)(dc + dr) * RDIM + c4 * 4);
      *reinterpret_cast<float4*>(&cs[dr][c4 * 4]) = v;
    }
    __syncthreads();
#pragma unroll 4
    for (int d = 0; d < 32; ++d) {
      const float x0 = xs[row0][d];
      const float x1 = xs[row1][d];
      const float4* cp = reinterpret_cast<const float4*>(&cs[d][rc * 16]);
      float cv[16];
      *reinterpret_cast<float4*>(&cv[0])  = cp[0];
      *reinterpret_cast<float4*>(&cv[4])  = cp[1];
      *reinterpret_cast<float4*>(&cv[8])  = cp[2];
      *reinterpret_cast<float4*>(&cv[12]) = cp[3];
#pragma unroll
      for (int j = 0; j < 16; ++j) { acc0[j] += x0 * cv[j]; acc1[j] += x1 * cv[j]; }
    }
    __syncthreads();
  }
  if (row0 < nrows) {
    const int tk = list_tk[base + row0];
    const float wg = out[OUT_W_OFF + tk];
    float* orow = out + OUT_O_OFF + (size_t)(tk >> 3) * RDIM + rc * 16;
#pragma unroll
    for (int j = 0; j < 16; ++j) unsafeAtomicAdd(&orow[j], acc0[j] * wg);
  }
  if (row1 < nrows) {
    const int tk = list_tk[base + row1];
    const float wg = out[OUT_W_OFF + tk];
    float* orow = out + OUT_O_OFF + (size_t)(tk >> 3) * RDIM + rc * 16;
#pragma unroll
    for (int j = 0; j < 16; ++j) unsafeAtomicAdd(&orow[j], acc1[j] * wg);
  }
}

// ---------------------------------------------------------------------------
extern "C" void kernel_launch(void* const* d_in, const int* in_sizes, int n_in,
                              void* d_out, int out_size, void* d_ws, size_t ws_size,
                              hipStream_t stream)
{
  (void)in_sizes; (void)n_in; (void)out_size;

  const float* x  = (const float*)d_in[0];
  const float* rw = (const float*)d_in[1];
  const float* cn = (const float*)d_in[2];
  float* out = (float*)d_out;

  char* wsb = (char*)d_ws;
  int* counts    = (int*)(wsb);
  int* offsets   = (int*)(wsb + 256);
  int* list_tk   = (int*)(wsb + 1024);
  int* idx_int   = (int*)(wsb + 263168);
  int* histT     = (int*)(wsb + 525312);   // [525312, 590848)
  int* chunk_off = (int*)(wsb + 590848);   // [590848, 656384)

  const size_t OFF_XBF  = 656384;
  const size_t SZ_XBF   = (size_t)T_TOK * DDIM * 2;
  const size_t SZ_CNBT  = (size_t)NEXP * RDIM * DDIM * 2;
  const size_t SZ_PROJ  = (size_t)T_TOK * TOPK * RDIM * 2;
  const size_t OFF_PART = OFF_XBF + SZ_XBF + SZ_CNBT + SZ_PROJ;
  u16* xbf    = (u16*)(wsb + OFF_XBF);
  u16* cnbt   = (u16*)(wsb + OFF_XBF + SZ_XBF);
  u16* projbf = (u16*)(wsb + OFF_XBF + SZ_XBF + SZ_CNBT);
  double* partials = (double*)(wsb + OFF_PART);

  const int tier = (ws_size >= OFF_PART) ? 0
                 : (ws_size >= OFF_XBF + SZ_XBF + SZ_CNBT) ? 1 : 2;

  // Router slicing: 8 slices (measured best), fallback 4 / single-pass.
  const size_t slice_bytes = (size_t)T_TOK * NEXP * sizeof(double);
  int nslice = 0;
  if (tier == 0 && ws_size >= OFF_PART + 8 * slice_bytes) nslice = 8;
  else if (tier == 0 && ws_size >= OFF_PART + 4 * slice_bytes) nslice = 4;

  if (tier != 0)
    hipMemsetAsync(d_out, 0, (size_t)T_TOK * RDIM * sizeof(float), stream);

  if (tier <= 1) {
    if (nslice == 0)
      convert_x_kernel<<<4096, 256, 0, stream>>>(x, xbf);
    convert_cn_kernel<<<dim3(NEXP, 32, 4), 256, 0, stream>>>(cn, cnbt);
  }

  if (nslice > 0) {
    router_part_kernel<<<dim3(T_TOK / 128, nslice), 256, 0, stream>>>(
        x, rw, partials, xbf, DDIM / nslice);
    topk_kernel<<<T_TOK / 4, 256, 0, stream>>>(partials, out, idx_int, nslice);
  } else {
    router_gemm_kernel<<<T_TOK / 32, 256, 0, stream>>>(x, rw, out);
    topk_kernel<<<T_TOK / 4, 256, 0, stream>>>(partials, out, idx_int, 0);
  }

  hist_kernel<<<NCHUNK, 256, 0, stream>>>(idx_int, histT);
  offsets_kernel<<<NEXP, 256, 0, stream>>>(histT, chunk_off, counts, offsets);
  scatter_kernel<<<NCHUNK, 256, 0, stream>>>(idx_int, chunk_off, list_tk);

  if (tier == 0) {
    dim3 grid(NEXP, 128);  // 64-row tiles; cnt <= 8192 -> 128 tiles cover all
    mfma_gemm_kernel<0><<<grid, 256, 0, stream>>>(xbf, cnbt, counts, offsets, list_tk, out, projbf);
    combine_kernel<<<T_TOK / 4, 256, 0, stream>>>(projbf, out);
  } else if (tier == 1) {
    dim3 grid(NEXP, 128);
    mfma_gemm_kernel<1><<<grid, 256, 0, stream>>>(xbf, cnbt, counts, offsets, list_tk, out, projbf);
  } else {
    dim3 grid(NEXP, 128);
    gemm_f32_kernel<<<grid, 256, 0, stream>>>(x, cn, counts, offsets, list_tk, out);
  }
}

// Round 19
// 117.969 us; speedup vs baseline: 1.0323x; 1.0323x over previous
//
#include <hip/hip_runtime.h>
#include <math.h>

typedef unsigned int  u32;
typedef unsigned short u16;
typedef unsigned long long u64;

// Problem constants (B=4, S=2048, D=1024, R=128, N=64, K=8)
#define T_TOK 8192
#define DDIM  1024
#define RDIM  128
#define NEXP  64
#define TOPK  8
#define NENT  (T_TOK * TOPK)   // 65536
#define NCHUNK 256             // chunks of 256 entries

// d_out layout (floats), reference return order: output, weights, topk_idx, scores
#define OUT_O_OFF 0
#define OUT_W_OFF (T_TOK * RDIM)                 // 1048576
#define OUT_I_OFF (OUT_W_OFF + T_TOK * TOPK)     // 1114112
#define OUT_S_OFF (OUT_I_OFF + T_TOK * TOPK)     // 1179648

// ws layout (bytes)
//   0        counts    int[64]
//   256      offsets   int[64]
//   1024     list_tk   int[65536]
//   263168   idx_int   int[65536]
//   525312   histT     int[64*256]   [525312, 590848)
//   590848   chunk_off int[64*256]   [590848, 656384)
//   656384   x_bf      u16[8192*1024]      (16 MB)
//   +16M     cn_bt     u16[64*128*1024]    (16 MB, [n][r][d])
//   +32M     proj_bf   u16[65536*128]      (16 MB)
//   +48M     partials  double[nslice][8192][64] (32 MB @ nslice=8)

typedef __attribute__((ext_vector_type(8))) short bf16x8;
typedef __attribute__((ext_vector_type(4))) float f32x4;

__device__ __forceinline__ u16 f2bf(float f) {
  union { float f; u32 u; } v; v.f = f;
  u32 r = v.u + 0x7fffu + ((v.u >> 16) & 1u);   // RNE
  return (u16)(r >> 16);
}
__device__ __forceinline__ float bf2f(u16 h) {
  union { u32 u; float f; } v; v.u = ((u32)h) << 16;
  return v.f;
}

// async global->LDS, 16B per lane; LDS dest = wave-uniform base + lane*16
#define GL_LDS(gp, lp) __builtin_amdgcn_global_load_lds( \
    (const __attribute__((address_space(1))) void*)(gp), \
    (__attribute__((address_space(3))) void*)(lp), 16, 0, 0)

// ---------------------------------------------------------------------------
// convert x fp32 -> bf16 (fallback path only; sliced router writes xbf itself)
// ---------------------------------------------------------------------------
__global__ __launch_bounds__(256) void convert_x_kernel(
    const float* __restrict__ x, u16* __restrict__ xbf)
{
  const int i = blockIdx.x * 256 + threadIdx.x;   // 0 .. 1048575
  const float4 a = reinterpret_cast<const float4*>(x)[i * 2];
  const float4 b = reinterpret_cast<const float4*>(x)[i * 2 + 1];
  uint4 o;
  o.x = (u32)f2bf(a.x) | ((u32)f2bf(a.y) << 16);
  o.y = (u32)f2bf(a.z) | ((u32)f2bf(a.w) << 16);
  o.z = (u32)f2bf(b.x) | ((u32)f2bf(b.y) << 16);
  o.w = (u32)f2bf(b.z) | ((u32)f2bf(b.w) << 16);
  reinterpret_cast<uint4*>(xbf)[i] = o;
}

// ---------------------------------------------------------------------------
// transpose+convert cn [n][d][r] fp32 -> cn_bt [n][r][d] bf16, 32x32 tiles
// ---------------------------------------------------------------------------
__global__ __launch_bounds__(256) void convert_cn_kernel(
    const float* __restrict__ cn, u16* __restrict__ cnbt)
{
  const int n  = blockIdx.x;
  const int d0 = blockIdx.y * 32;
  const int r0 = blockIdx.z * 32;
  __shared__ float ts[32][33];
  const int t = threadIdx.x;
  {
    const int dr = t >> 3, rq = t & 7;
    float4 v = *reinterpret_cast<const float4*>(
        cn + ((size_t)n * DDIM + d0 + dr) * RDIM + r0 + rq * 4);
    ts[dr][rq * 4 + 0] = v.x; ts[dr][rq * 4 + 1] = v.y;
    ts[dr][rq * 4 + 2] = v.z; ts[dr][rq * 4 + 3] = v.w;
  }
  __syncthreads();
  {
    const int rr = t >> 3, dq = t & 7;
    ushort4 o;
    o.x = f2bf(ts[dq * 4 + 0][rr]);
    o.y = f2bf(ts[dq * 4 + 1][rr]);
    o.z = f2bf(ts[dq * 4 + 2][rr]);
    o.w = f2bf(ts[dq * 4 + 3][rr]);
    *reinterpret_cast<ushort4*>(
        cnbt + ((size_t)n * RDIM + r0 + rr) * DDIM + d0 + dq * 4) = o;
  }
}

// ---------------------------------------------------------------------------
// Router v4 (MEASURED BEST across 7 variants: 41 us): fp64 LDS converted
// once at staging, double2 reads, 64-token tile, 32-d chunks (stride 38 ->
// 38.9 KB LDS), thread = 4 tok x 4 exp, nslice=8.  Bit-identical scores.
// Fused bf16 x side-write.
// ---------------------------------------------------------------------------
__global__ __launch_bounds__(256) void router_part_kernel(
    const float* __restrict__ x, const float* __restrict__ rw,
    double* __restrict__ partials, u16* __restrict__ xbf, int dlen)
{
  __shared__ double xs[64][38];
  __shared__ double wsd[64][38];

  const int tok0  = blockIdx.x * 64;
  const int slice = blockIdx.y;
  const int d0    = slice * dlen;
  const int t     = threadIdx.x;
  const int ti    = t & 15;
  const int ei    = t >> 4;

  const int srow = t >> 2;        // 0..63
  const int sq   = t & 3;

  double acc[4][4];
#pragma unroll
  for (int a = 0; a < 4; ++a)
#pragma unroll
    for (int b = 0; b < 4; ++b) acc[a][b] = 0.0;

  for (int dc = d0; dc < d0 + dlen; dc += 32) {
#pragma unroll
    for (int i = 0; i < 2; ++i) {
      const int dd = sq * 4 + i * 16;
      float4 v = *reinterpret_cast<const float4*>(
          x + (size_t)(tok0 + srow) * DDIM + dc + dd);
      double2 p0; p0.x = (double)v.x; p0.y = (double)v.y;
      double2 p1; p1.x = (double)v.z; p1.y = (double)v.w;
      *reinterpret_cast<double2*>(&xs[srow][dd])     = p0;
      *reinterpret_cast<double2*>(&xs[srow][dd + 2]) = p1;
      ushort4 o;
      o.x = f2bf(v.x); o.y = f2bf(v.y); o.z = f2bf(v.z); o.w = f2bf(v.w);
      *reinterpret_cast<ushort4*>(
          xbf + (size_t)(tok0 + srow) * DDIM + dc + dd) = o;

      float4 wv = *reinterpret_cast<const float4*>(
          rw + (size_t)srow * DDIM + dc + dd);
      double2 q0; q0.x = (double)wv.x; q0.y = (double)wv.y;
      double2 q1; q1.x = (double)wv.z; q1.y = (double)wv.w;
      *reinterpret_cast<double2*>(&wsd[srow][dd])     = q0;
      *reinterpret_cast<double2*>(&wsd[srow][dd + 2]) = q1;
    }
    __syncthreads();

#pragma unroll 4
    for (int d2 = 0; d2 < 32; d2 += 2) {
      double2 xv0 = *reinterpret_cast<const double2*>(&xs[ti +  0][d2]);
      double2 xv1 = *reinterpret_cast<const double2*>(&xs[ti + 16][d2]);
      double2 xv2 = *reinterpret_cast<const double2*>(&xs[ti + 32][d2]);
      double2 xv3 = *reinterpret_cast<const double2*>(&xs[ti + 48][d2]);
      double2 wv0 = *reinterpret_cast<const double2*>(&wsd[ei +  0][d2]);
      double2 wv1 = *reinterpret_cast<const double2*>(&wsd[ei + 16][d2]);
      double2 wv2 = *reinterpret_cast<const double2*>(&wsd[ei + 32][d2]);
      double2 wv3 = *reinterpret_cast<const double2*>(&wsd[ei + 48][d2]);
      acc[0][0] += xv0.x * wv0.x; acc[0][0] += xv0.y * wv0.y;
      acc[0][1] += xv0.x * wv1.x; acc[0][1] += xv0.y * wv1.y;
      acc[0][2] += xv0.x * wv2.x; acc[0][2] += xv0.y * wv2.y;
      acc[0][3] += xv0.x * wv3.x; acc[0][3] += xv0.y * wv3.y;
      acc[1][0] += xv1.x * wv0.x; acc[1][0] += xv1.y * wv0.y;
      acc[1][1] += xv1.x * wv1.x; acc[1][1] += xv1.y * wv1.y;
      acc[1][2] += xv1.x * wv2.x; acc[1][2] += xv1.y * wv2.y;
      acc[1][3] += xv1.x * wv3.x; acc[1][3] += xv1.y * wv3.y;
      acc[2][0] += xv2.x * wv0.x; acc[2][0] += xv2.y * wv0.y;
      acc[2][1] += xv2.x * wv1.x; acc[2][1] += xv2.y * wv1.y;
      acc[2][2] += xv2.x * wv2.x; acc[2][2] += xv2.y * wv2.y;
      acc[2][3] += xv2.x * wv3.x; acc[2][3] += xv2.y * wv3.y;
      acc[3][0] += xv3.x * wv0.x; acc[3][0] += xv3.y * wv0.y;
      acc[3][1] += xv3.x * wv1.x; acc[3][1] += xv3.y * wv1.y;
      acc[3][2] += xv3.x * wv2.x; acc[3][2] += xv3.y * wv2.y;
      acc[3][3] += xv3.x * wv3.x; acc[3][3] += xv3.y * wv3.y;
    }
    __syncthreads();
  }

#pragma unroll
  for (int jt = 0; jt < 4; ++jt)
#pragma unroll
    for (int je = 0; je < 4; ++je)
      partials[((size_t)slice * T_TOK + tok0 + ti + 16 * jt) * NEXP
               + ei + 16 * je] = acc[jt][je];
}

// ---------------------------------------------------------------------------
// Fallback single-pass router (round-5/6 proven): fp32 LDS, fp64 acc.
// ---------------------------------------------------------------------------
__global__ __launch_bounds__(256) void router_gemm_kernel(
    const float* __restrict__ x, const float* __restrict__ rw,
    float* __restrict__ out)
{
  __shared__ float xs[32][68];
  __shared__ float wsm[64][68];
  const int tok0 = blockIdx.x * 32;
  const int t  = threadIdx.x;
  const int ti2 = (t & 15) * 2;
  const int e4  = (t >> 4) * 4;

  double acc[2][4];
#pragma unroll
  for (int a = 0; a < 2; ++a)
#pragma unroll
    for (int b = 0; b < 4; ++b) acc[a][b] = 0.0;

  for (int dc = 0; dc < DDIM; dc += 64) {
#pragma unroll
    for (int p = 0; p < 2; ++p) {
      const int idx = t + p * 256;
      const int row = idx >> 4, q = idx & 15;
      float4 v = *reinterpret_cast<const float4*>(
          x + (size_t)(tok0 + row) * DDIM + dc + q * 4);
      *reinterpret_cast<float4*>(&xs[row][q * 4]) = v;
    }
#pragma unroll
    for (int p = 0; p < 4; ++p) {
      const int idx = t + p * 256;
      const int row = idx >> 4, q = idx & 15;
      float4 v = *reinterpret_cast<const float4*>(
          rw + (size_t)row * DDIM + dc + q * 4);
      *reinterpret_cast<float4*>(&wsm[row][q * 4]) = v;
    }
    __syncthreads();

#pragma unroll 2
    for (int d4 = 0; d4 < 64; d4 += 4) {
      float4 xv0 = *reinterpret_cast<const float4*>(&xs[ti2][d4]);
      float4 xv1 = *reinterpret_cast<const float4*>(&xs[ti2 + 1][d4]);
      float4 wv0 = *reinterpret_cast<const float4*>(&wsm[e4 + 0][d4]);
      float4 wv1 = *reinterpret_cast<const float4*>(&wsm[e4 + 1][d4]);
      float4 wv2 = *reinterpret_cast<const float4*>(&wsm[e4 + 2][d4]);
      float4 wv3 = *reinterpret_cast<const float4*>(&wsm[e4 + 3][d4]);
      acc[0][0] += (double)xv0.x * (double)wv0.x; acc[0][0] += (double)xv0.y * (double)wv0.y;
      acc[0][0] += (double)xv0.z * (double)wv0.z; acc[0][0] += (double)xv0.w * (double)wv0.w;
      acc[0][1] += (double)xv0.x * (double)wv1.x; acc[0][1] += (double)xv0.y * (double)wv1.y;
      acc[0][1] += (double)xv0.z * (double)wv1.z; acc[0][1] += (double)xv0.w * (double)wv1.w;
      acc[0][2] += (double)xv0.x * (double)wv2.x; acc[0][2] += (double)xv0.y * (double)wv2.y;
      acc[0][2] += (double)xv0.z * (double)wv2.z; acc[0][2] += (double)xv0.w * (double)wv2.w;
      acc[0][3] += (double)xv0.x * (double)wv3.x; acc[0][3] += (double)xv0.y * (double)wv3.y;
      acc[0][3] += (double)xv0.z * (double)wv3.z; acc[0][3] += (double)xv0.w * (double)wv3.w;
      acc[1][0] += (double)xv1.x * (double)wv0.x; acc[1][0] += (double)xv1.y * (double)wv0.y;
      acc[1][0] += (double)xv1.z * (double)wv0.z; acc[1][0] += (double)xv1.w * (double)wv0.w;
      acc[1][1] += (double)xv1.x * (double)wv1.x; acc[1][1] += (double)xv1.y * (double)wv1.y;
      acc[1][1] += (double)xv1.z * (double)wv1.z; acc[1][1] += (double)xv1.w * (double)wv1.w;
      acc[1][2] += (double)xv1.x * (double)wv2.x; acc[1][2] += (double)xv1.y * (double)wv2.y;
      acc[1][2] += (double)xv1.z * (double)wv2.z; acc[1][2] += (double)xv1.w * (double)wv2.w;
      acc[1][3] += (double)xv1.x * (double)wv3.x; acc[1][3] += (double)xv1.y * (double)wv3.y;
      acc[1][3] += (double)xv1.z * (double)wv3.z; acc[1][3] += (double)xv1.w * (double)wv3.w;
    }
    __syncthreads();
  }

#pragma unroll
  for (int a = 0; a < 2; ++a) {
    float4 o;
    o.x = (float)acc[a][0]; o.y = (float)acc[a][1];
    o.z = (float)acc[a][2]; o.w = (float)acc[a][3];
    *reinterpret_cast<float4*>(
        out + OUT_S_OFF + (size_t)(tok0 + ti2 + a) * NEXP + e4) = o;
  }
}

// ---------------------------------------------------------------------------
// Top-8 + softmax. 4 tokens per 256-thread block (one wave each). No atomics.
// ---------------------------------------------------------------------------
__global__ __launch_bounds__(256) void topk_kernel(
    const double* __restrict__ partials,
    float* __restrict__ out, int* __restrict__ idx_int, int nslice)
{
  const int token = blockIdx.x * 4 + (threadIdx.x >> 6);
  const int lane  = threadIdx.x & 63;

  float v;
  if (nslice > 0) {
    double s = 0.0;
    for (int sl = 0; sl < nslice; ++sl)
      s += partials[((size_t)sl * T_TOK + token) * NEXP + lane];
    v = (float)s;
    out[OUT_S_OFF + (size_t)token * NEXP + lane] = v;
  } else {
    v = out[OUT_S_OFF + (size_t)token * NEXP + lane];
  }

  float cur = v;
  float topv[TOPK];
  int   topi[TOPK];
  for (int k = 0; k < TOPK; ++k) {
    float bv = cur;
    int   bi = lane;
#pragma unroll
    for (int off = 32; off >= 1; off >>= 1) {
      float ov = __shfl_xor(bv, off);
      int   oi = __shfl_xor(bi, off);
      if (ov > bv || (ov == bv && oi < bi)) { bv = ov; bi = oi; }
    }
    topv[k] = bv;
    topi[k] = bi;
    if (lane == bi) cur = -INFINITY;
  }
  const float m = topv[0];
  float wk[TOPK];
  float s = 0.f;
#pragma unroll
  for (int k = 0; k < TOPK; ++k) { wk[k] = expf(topv[k] - m); s += wk[k]; }
  const float inv = 1.f / s;

  if (lane < TOPK) {
    out[OUT_W_OFF + (size_t)token * TOPK + lane] = wk[lane] * inv;
    out[OUT_I_OFF + (size_t)token * TOPK + lane] = (float)topi[lane];
    idx_int[(size_t)token * TOPK + lane] = topi[lane];
  }
}

// ---------------------------------------------------------------------------
// Compaction phase A: per-chunk expert histogram (ballot, no atomics).
// ---------------------------------------------------------------------------
__global__ __launch_bounds__(256) void hist_kernel(
    const int* __restrict__ idx_int, int* __restrict__ histT)
{
  const int chunk = blockIdx.x;
  const int t = threadIdx.x;
  const int w = t >> 6, l = t & 63;
  const int v = idx_int[chunk * 256 + t];

  __shared__ int wh[4][64];
  int cnt = 0;
#pragma unroll 8
  for (int s = 0; s < NEXP; ++s) {
    const u64 b = __ballot(v == s);
    if (l == s) cnt = (int)__popcll(b);
  }
  wh[w][l] = cnt;
  __syncthreads();
  if (t < NEXP)
    histT[t * NCHUNK + chunk] = wh[0][t] + wh[1][t] + wh[2][t] + wh[3][t];
}

// ---------------------------------------------------------------------------
// Compaction phase B, PARALLEL: 64 blocks (one per expert).
// ---------------------------------------------------------------------------
__global__ __launch_bounds__(256) void offsets_kernel(
    const int* __restrict__ histT, int* __restrict__ chunk_off,
    int* __restrict__ counts, int* __restrict__ offsets)
{
  const int n = blockIdx.x;
  const int t = threadIdx.x;
  const int w = t >> 6, l = t & 63;
  __shared__ int bsum[4];
  __shared__ int wsum[4];

  int part = 0;
  for (int i = t; i < n * NCHUNK; i += 256) part += histT[i];
#pragma unroll
  for (int off = 32; off >= 1; off >>= 1) part += __shfl_xor(part, off);
  if (l == 0) bsum[w] = part;
  __syncthreads();
  const int base = bsum[0] + bsum[1] + bsum[2] + bsum[3];

  const int h = histT[n * NCHUNK + t];
  int s = h;
#pragma unroll
  for (int off = 1; off < 64; off <<= 1) {
    const int o = __shfl_up(s, off);
    if (l >= off) s += o;
  }
  if (l == 63) wsum[w] = s;
  __syncthreads();
  int wpre = 0;
#pragma unroll
  for (int w2 = 0; w2 < 4; ++w2) if (w2 < w) wpre += wsum[w2];
  const int incl = s + wpre;

  chunk_off[n * NCHUNK + t] = base + incl - h;
  if (t == 255) counts[n] = incl;
  if (t == 0)   offsets[n] = base;
}

// ---------------------------------------------------------------------------
// Compaction phase C: stable scatter via ballot rank + per-wave hist prefix.
// ---------------------------------------------------------------------------
__global__ __launch_bounds__(256) void scatter_kernel(
    const int* __restrict__ idx_int, const int* __restrict__ chunk_off,
    int* __restrict__ list_tk)
{
  const int chunk = blockIdx.x;
  const int t = threadIdx.x;
  const int w = t >> 6, l = t & 63;
  const int e = chunk * 256 + t;
  const int v = idx_int[e];

  __shared__ int wh[4][64];
  int myrank = 0, cnt = 0;
#pragma unroll 8
  for (int s = 0; s < NEXP; ++s) {
    const u64 b = __ballot(v == s);
    if (v == s) myrank = (int)__popcll(b & ((1ull << l) - 1ull));
    if (l == s) cnt = (int)__popcll(b);
  }
  wh[w][l] = cnt;
  __syncthreads();
  int pre = 0;
#pragma unroll
  for (int w2 = 0; w2 < 4; ++w2) if (w2 < w) pre += wh[w2][v];
  list_tk[chunk_off[v * NCHUNK + chunk] + pre + myrank] = e;
}

// ---------------------------------------------------------------------------
// MFMA expert GEMM v4 (round-14/15 proven) + T5 setprio around MFMA cluster.
// 64-token tile, 48 KB dbuf LDS, pre-swizzled GL_LDS, counted-vmcnt pipeline.
// ---------------------------------------------------------------------------
template<int MODE>
__global__ __launch_bounds__(256) void mfma_gemm_kernel(
    const u16* __restrict__ xbf, const u16* __restrict__ cnbt,
    const int* __restrict__ counts, const int* __restrict__ offsets,
    const int* __restrict__ list_tk,
    float* __restrict__ out, u16* __restrict__ projbf)
{
  const int n = blockIdx.x;
  const int cnt = counts[n];
  const int start = blockIdx.y * 64;
  if (start >= cnt) return;
  const int nrows = min(64, cnt - start);
  const int base = offsets[n] + start;

  __shared__ __align__(16) u16 smem[2 * 12288];   // 48 KB

  const int t  = threadIdx.x;
  const int l  = t & 63;
  const int w  = t >> 6;
  const int cl = l & 15;
  const int kq = l >> 4;

  const int rsub = l >> 3;                 // 0..7
  const int p8   = ((l & 7) ^ rsub) * 8;   // swizzled u16 offset in row

  int toki[2];
#pragma unroll
  for (int i = 0; i < 2; ++i) {
    const int r = w * 16 + i * 8 + rsub;
    toki[i] = list_tk[base + min(r, nrows - 1)] >> 3;
  }
  const u16* cnb = cnbt + (size_t)n * RDIM * DDIM;

  f32x4 acc[8];
#pragma unroll
  for (int f = 0; f < 8; ++f) acc[f] = (f32x4){0.f, 0.f, 0.f, 0.f};

  // prologue: stage chunk 0 into buffer 0 (6 GL_LDS per thread)
#pragma unroll
  for (int i = 0; i < 2; ++i) {
    const int rs = w * 16 + i * 8;
    GL_LDS(xbf + (size_t)toki[i] * DDIM + p8, smem + rs * 64);
  }
#pragma unroll
  for (int i = 0; i < 4; ++i) {
    const int rs = w * 32 + i * 8;
    GL_LDS(cnb + (size_t)(rs + rsub) * DDIM + p8, smem + 4096 + rs * 64);
  }

  int cur = 0;
  for (int c = 0; c < 16; ++c) {
    if (c < 15) {
      const int dc = (c + 1) * 64;
      const int po = (cur ^ 1) * 12288;
#pragma unroll
      for (int i = 0; i < 2; ++i) {
        const int rs = w * 16 + i * 8;
        GL_LDS(xbf + (size_t)toki[i] * DDIM + dc + p8, smem + po + rs * 64);
      }
#pragma unroll
      for (int i = 0; i < 4; ++i) {
        const int rs = w * 32 + i * 8;
        GL_LDS(cnb + (size_t)(rs + rsub) * DDIM + dc + p8,
               smem + po + 4096 + rs * 64);
      }
      asm volatile("s_waitcnt vmcnt(6)" ::: "memory");
    } else {
      asm volatile("s_waitcnt vmcnt(0)" ::: "memory");
    }
    __builtin_amdgcn_s_barrier();          // all waves' chunk-c data in LDS
    __builtin_amdgcn_sched_barrier(0);     // pin: no ds_read hoists above

    const u16* A = smem + cur * 12288;
    const u16* B = A + 4096;
    __builtin_amdgcn_s_setprio(1);
#pragma unroll
    for (int ks = 0; ks < 2; ++ks) {
      const int piece = ks * 4 + kq;
      const int ar = w * 16 + cl;
      bf16x8 a = *reinterpret_cast<const bf16x8*>(
          &A[ar * 64 + ((piece ^ (ar & 7)) * 8)]);
#pragma unroll
      for (int f = 0; f < 8; ++f) {
        const int br = f * 16 + cl;
        bf16x8 b = *reinterpret_cast<const bf16x8*>(
            &B[br * 64 + ((piece ^ (br & 7)) * 8)]);
        acc[f] = __builtin_amdgcn_mfma_f32_16x16x32_bf16(a, b, acc[f], 0, 0, 0);
      }
    }
    __builtin_amdgcn_s_setprio(0);
    asm volatile("s_waitcnt lgkmcnt(0)" ::: "memory");  // reads of cur done
    __builtin_amdgcn_s_barrier();          // before next iter overwrites cur
    cur ^= 1;
  }

  // epilogue: C/D layout row=(l>>4)*4+reg, col = f*16 + (l&15)
#pragma unroll
  for (int j = 0; j < 4; ++j) {
    const int row = w * 16 + kq * 4 + j;
    if (row < nrows) {
      const int tk = list_tk[base + row];
      if (MODE == 0) {
        u16* prow = projbf + (size_t)tk * RDIM + cl;
#pragma unroll
        for (int f = 0; f < 8; ++f) prow[f * 16] = f2bf(acc[f][j]);
      } else {
        const float wg = out[OUT_W_OFF + tk];
        float* orow = out + OUT_O_OFF + (size_t)(tk >> 3) * RDIM + cl;
#pragma unroll
        for (int f = 0; f < 8; ++f) unsafeAtomicAdd(&orow[f * 16], wg * acc[f][j]);
      }
    }
  }
}

// ---------------------------------------------------------------------------
// Combine: out[tok][r] = sum_k w[tok][k] * proj[tok*8+k][r].  Wave per token.
// ---------------------------------------------------------------------------
__global__ __launch_bounds__(256) void combine_kernel(
    const u16* __restrict__ projbf, float* __restrict__ out)
{
  const int token = blockIdx.x * 4 + (threadIdx.x >> 6);
  const int l = threadIdx.x & 63;
  float wts[TOPK];
#pragma unroll
  for (int k = 0; k < TOPK; ++k) wts[k] = out[OUT_W_OFF + (size_t)token * TOPK + k];
  float s0 = 0.f, s1 = 0.f;
#pragma unroll
  for (int k = 0; k < TOPK; ++k) {
    const u32 u = *reinterpret_cast<const u32*>(
        projbf + ((size_t)token * TOPK + k) * RDIM + l * 2);
    s0 += wts[k] * bf2f((u16)(u & 0xffff));
    s1 += wts[k] * bf2f((u16)(u >> 16));
  }
  float2 o; o.x = s0; o.y = s1;
  *reinterpret_cast<float2*>(out + OUT_O_OFF + (size_t)token * RDIM + l * 2) = o;
}

// ---------------------------------------------------------------------------
// Tier-2 fallback: fp32 gemm, weight read via tk (64-row tile, grid y=128).
// ---------------------------------------------------------------------------
__global__ __launch_bounds__(256) void gemm_f32_kernel(
    const float* __restrict__ x, const float* __restrict__ cn,
    const int* __restrict__ counts, const int* __restrict__ offsets,
    const int* __restrict__ list_tk, float* __restrict__ out)
{
  const int n = blockIdx.x;
  const int cnt = counts[n];
  const int start = blockIdx.y * 64;
  if (start >= cnt) return;
  const int nrows = min(64, cnt - start);
  const int base = offsets[n] + start;

  __shared__ float xs[64][33];
  __shared__ float cs[32][RDIM];

  const int t  = threadIdx.x;
  const int tg = t & 31;
  const int rc = t >> 5;
  const int row0 = tg * 2, row1 = tg * 2 + 1;
  const int rA = t >> 3, rB = rA + 32, jA = t & 7;
  const int tokA = (rA < nrows) ? (list_tk[base + rA] >> 3) : -1;
  const int tokB = (rB < nrows) ? (list_tk[base + rB] >> 3) : -1;

  float acc0[16], acc1[16];
#pragma unroll
  for (int j = 0; j < 16; ++j) { acc0[j] = 0.f; acc1[j] = 0.f; }
  const float* cbase = cn + (size_t)n * DDIM * RDIM;

  for (int dc = 0; dc < DDIM; dc += 32) {
    {
      float4 v = make_float4(0.f, 0.f, 0.f, 0.f);
      if (tokA >= 0) v = *reinterpret_cast<const float4*>(x + (size_t)tokA * DDIM + dc + jA * 4);
      xs[rA][jA * 4 + 0] = v.x; xs[rA][jA * 4 + 1] = v.y;
      xs[rA][jA * 4 + 2] = v.z; xs[rA][jA * 4 + 3] = v.w;
      float4 u = make_float4(0.f, 0.f, 0.f, 0.f);
      if (tokB >= 0) u = *reinterpret_cast<const float4*>(x + (size_t)tokB * DDIM + dc + jA * 4);
      xs[rB][jA * 4 + 0] = u.x; xs[rB][jA * 4 + 1] = u.y;
      xs[rB][jA * 4 + 2] = u.z; xs[rB][jA * 4 + 3] = u.w;
    }
#pragma unroll
    for (int p = 0; p < 4; ++p) {
      const int f = t + p * 256;
      const int dr = f >> 5, c4 = f & 31;
      float4 v = *reinterpret_cast<const float4*>(cbase + (size_t)(dc + dr) * RDIM + c4 * 4);
      *reinterpret_cast<float4*>(&cs[dr][c4 * 4]) = v;
    }
    __syncthreads();
#pragma unroll 4
    for (int d = 0; d < 32; ++d) {
      const float x0 = xs[row0][d];
      const float x1 = xs[row1][d];
      const float4* cp = reinterpret_cast<const float4*>(&cs[d][rc * 16]);
      float cv[16];
      *reinterpret_cast<float4*>(&cv[0])  = cp[0];
      *reinterpret_cast<float4*>(&cv[4])  = cp[1];
      *reinterpret_cast<float4*>(&cv[8])  = cp[2];
      *reinterpret_cast<float4*>(&cv[12]) = cp[3];
#pragma unroll
      for (int j = 0; j < 16; ++j) { acc0[j] += x0 * cv[j]; acc1[j] += x1 * cv[j]; }
    }
    __syncthreads();
  }
  if (row0 < nrows) {
    const int tk = list_tk[base + row0];
    const float wg = out[OUT_W_OFF + tk];
    float* orow = out + OUT_O_OFF + (size_t)(tk >> 3) * RDIM + rc * 16;
#pragma unroll
    for (int j = 0; j < 16; ++j) unsafeAtomicAdd(&orow[j], acc0[j] * wg);
  }
  if (row1 < nrows) {
    const int tk = list_tk[base + row1];
    const float wg = out[OUT_W_OFF + tk];
    float* orow = out + OUT_O_OFF + (size_t)(tk >> 3) * RDIM + rc * 16;
#pragma unroll
    for (int j = 0; j < 16; ++j) unsafeAtomicAdd(&orow[j], acc1[j] * wg);
  }
}

// ---------------------------------------------------------------------------
extern "C" void kernel_launch(void* const* d_in, const int* in_sizes, int n_in,
                              void* d_out, int out_size, void* d_ws, size_t ws_size,
                              hipStream_t stream)
{
  (void)in_sizes; (void)n_in; (void)out_size;

  const float* x  = (const float*)d_in[0];
  const float* rw = (const float*)d_in[1];
  const float* cn = (const float*)d_in[2];
  float* out = (float*)d_out;

  char* wsb = (char*)d_ws;
  int* counts    = (int*)(wsb);
  int* offsets   = (int*)(wsb + 256);
  int* list_tk   = (int*)(wsb + 1024);
  int* idx_int   = (int*)(wsb + 263168);
  int* histT     = (int*)(wsb + 525312);   // [525312, 590848)
  int* chunk_off = (int*)(wsb + 590848);   // [590848, 656384)

  const size_t OFF_XBF  = 656384;
  const size_t SZ_XBF   = (size_t)T_TOK * DDIM * 2;
  const size_t SZ_CNBT  = (size_t)NEXP * RDIM * DDIM * 2;
  const size_t SZ_PROJ  = (size_t)T_TOK * TOPK * RDIM * 2;
  const size_t OFF_PART = OFF_XBF + SZ_XBF + SZ_CNBT + SZ_PROJ;
  u16* xbf    = (u16*)(wsb + OFF_XBF);
  u16* cnbt   = (u16*)(wsb + OFF_XBF + SZ_XBF);
  u16* projbf = (u16*)(wsb + OFF_XBF + SZ_XBF + SZ_CNBT);
  double* partials = (double*)(wsb + OFF_PART);

  const int tier = (ws_size >= OFF_PART) ? 0
                 : (ws_size >= OFF_XBF + SZ_XBF + SZ_CNBT) ? 1 : 2;

  // Router slicing: 8 slices (measured best), fallback 4 / single-pass.
  const size_t slice_bytes = (size_t)T_TOK * NEXP * sizeof(double);
  int nslice = 0;
  if (tier == 0 && ws_size >= OFF_PART + 8 * slice_bytes) nslice = 8;
  else if (tier == 0 && ws_size >= OFF_PART + 4 * slice_bytes) nslice = 4;

  if (tier != 0)
    hipMemsetAsync(d_out, 0, (size_t)T_TOK * RDIM * sizeof(float), stream);

  if (tier <= 1) {
    if (nslice == 0)
      convert_x_kernel<<<4096, 256, 0, stream>>>(x, xbf);
    convert_cn_kernel<<<dim3(NEXP, 32, 4), 256, 0, stream>>>(cn, cnbt);
  }

  if (nslice > 0) {
    router_part_kernel<<<dim3(T_TOK / 64, nslice), 256, 0, stream>>>(
        x, rw, partials, xbf, DDIM / nslice);
    topk_kernel<<<T_TOK / 4, 256, 0, stream>>>(partials, out, idx_int, nslice);
  } else {
    router_gemm_kernel<<<T_TOK / 32, 256, 0, stream>>>(x, rw, out);
    topk_kernel<<<T_TOK / 4, 256, 0, stream>>>(partials, out, idx_int, 0);
  }

  hist_kernel<<<NCHUNK, 256, 0, stream>>>(idx_int, histT);
  offsets_kernel<<<NEXP, 256, 0, stream>>>(histT, chunk_off, counts, offsets);
  scatter_kernel<<<NCHUNK, 256, 0, stream>>>(idx_int, chunk_off, list_tk);

  if (tier == 0) {
    dim3 grid(NEXP, 128);  // 64-row tiles; cnt <= 8192 -> 128 tiles cover all
    mfma_gemm_kernel<0><<<grid, 256, 0, stream>>>(xbf, cnbt, counts, offsets, list_tk, out, projbf);
    combine_kernel<<<T_TOK / 4, 256, 0, stream>>>(projbf, out);
  } else if (tier == 1) {
    dim3 grid(NEXP, 128);
    mfma_gemm_kernel<1><<<grid, 256, 0, stream>>>(xbf, cnbt, counts, offsets, list_tk, out, projbf);
  } else {
    dim3 grid(NEXP, 128);
    gemm_f32_kernel<<<grid, 256, 0, stream>>>(x, cn, counts, offsets, list_tk, out);
  }
}